// Round 20
// baseline (294.275 us; speedup 1.0000x reference)
//
#include <hip/hip_runtime.h>
#include <cstddef>

#define Nn 50000
#define Ee 500000
#define INC 128
#define HC 256      // HEADS*OUT_C
#define OUTC 64
#define EDIM 32
#define NEG 0.2f
#define NB 196      // scan blocks = ceil(Nn/256)
#define GEMMB 782   // gemm blocks = ceil(Nn/64)

typedef __attribute__((ext_vector_type(8))) short short8;   // 8 bf16 = 4 VGPR
typedef __attribute__((ext_vector_type(4))) float f32x4;
typedef __attribute__((ext_vector_type(2))) float f32x2;

// ---- bf16 helpers (RNE) ----
__device__ __forceinline__ unsigned short f2bf(float f) {
    unsigned u = __float_as_uint(f);
    return (unsigned short)((u + 0x7FFFu + ((u >> 16) & 1u)) >> 16);
}
__device__ __forceinline__ float bf2f(unsigned short v) {
    return __uint_as_float(((unsigned)v) << 16);
}

// ---- 16-lane row sum via DPP butterfly (pure VALU, no DS pipe) ----
__device__ __forceinline__ float row_sum16(float x) {
    int i;
    i = __builtin_amdgcn_mov_dpp(__float_as_int(x), 0xB1, 0xF, 0xF, true);
    x += __int_as_float(i);
    i = __builtin_amdgcn_mov_dpp(__float_as_int(x), 0x4E, 0xF, 0xF, true);
    x += __int_as_float(i);
    i = __builtin_amdgcn_mov_dpp(__float_as_int(x), 0x141, 0xF, 0xF, true);
    x += __int_as_float(i);
    i = __builtin_amdgcn_mov_dpp(__float_as_int(x), 0x140, 0xF, 0xF, true);
    x += __int_as_float(i);
    return x;
}

// ---- K_pack: Wl/Wr (T-perm) + We (cb-perm) + deg zeroing (fused) ----
__global__ __launch_bounds__(256) void pack_kernel(
    const float* __restrict__ Wl, const float* __restrict__ Wr,
    const float* __restrict__ We,
    unsigned short* __restrict__ wlf, unsigned short* __restrict__ wrf,
    unsigned short* __restrict__ wef, int* __restrict__ deg)
{
    int sid = blockIdx.x * 256 + threadIdx.x;
    if (sid >= 9216) {                 // fused deg zeroing
        int i = sid - 9216;
        if (i < Nn) deg[i] = 0;
        return;
    }
    const float* W; unsigned short* dst; int s; int col; int k0;
    if (sid < 8192) {
        if (sid < 4096) { W = Wl; dst = wlf; s = sid; }
        else            { W = Wr; dst = wrf; s = sid - 4096; }
        int lane = s & 63;
        int T    = (s >> 6) & 15;
        int kc   = s >> 10;
        col = (lane & 15) * 16 + T;
        k0  = kc * 32 + (lane >> 4) * 8;
    } else {
        W = We; dst = wef; s = sid - 8192;
        int lane = s & 63;
        int nt   = (s >> 6) & 3;
        int cb   = s >> 8;
        col = cb * 64 + (lane & 15) * 4 + nt;
        k0  = (lane >> 4) * 8;
    }
    unsigned short tmp[8];
    #pragma unroll
    for (int j = 0; j < 8; ++j) tmp[j] = f2bf(W[(size_t)(k0 + j) * HC + col]);
    *(uint4*)(dst + (size_t)s * 8) = *(uint4*)tmp;
}

// ---- K1: fused gemm (both W, X read once) + hist blocks ----
__global__ __launch_bounds__(256) void gemm_hist_kernel(
    const float* __restrict__ X,
    const unsigned short* __restrict__ wlf, const float* __restrict__ bl,
    const unsigned short* __restrict__ wrf, const float* __restrict__ br,
    unsigned short* __restrict__ Ylb, unsigned short* __restrict__ Yrb,
    const int* __restrict__ ei, int* __restrict__ deg)
{
    if (blockIdx.x >= GEMMB) {
        int e = (blockIdx.x - GEMMB) * 256 + threadIdx.x;
        if (e < Ee) atomicAdd(deg + ei[Ee + e], 1);
        return;
    }

    const int tid = threadIdx.x, lane = tid & 63;
    const int l15 = lane & 15, l4 = lane >> 4;
    const int r0 = blockIdx.x * 64 + (tid >> 6) * 16;

    int arow = r0 + l15; if (arow >= Nn) arow = Nn - 1;
    short8 af[4];
    #pragma unroll
    for (int kc = 0; kc < 4; ++kc) {
        const f32x4* p = (const f32x4*)(X + (size_t)arow * INC + kc * 32 + l4 * 8);
        f32x4 v0 = p[0], v1 = p[1];
        short8 a;
        a[0]=(short)f2bf(v0.x); a[1]=(short)f2bf(v0.y); a[2]=(short)f2bf(v0.z); a[3]=(short)f2bf(v0.w);
        a[4]=(short)f2bf(v1.x); a[5]=(short)f2bf(v1.y); a[6]=(short)f2bf(v1.z); a[7]=(short)f2bf(v1.w);
        af[kc] = a;
    }

    #pragma unroll 1
    for (int w = 0; w < 2; ++w) {
        const unsigned short* wf = w ? wrf : wlf;
        const float* b = w ? br : bl;
        unsigned short* Yb = w ? Yrb : Ylb;

        f32x4 acc[16];
        #pragma unroll
        for (int T = 0; T < 16; ++T) acc[T] = (f32x4){0.f, 0.f, 0.f, 0.f};

        #pragma unroll
        for (int kc = 0; kc < 4; ++kc) {
            #pragma unroll
            for (int T = 0; T < 16; ++T) {
                short8 bf = *(const short8*)(wf + ((size_t)(kc * 16 + T) * 64 + lane) * 8);
                acc[T] = __builtin_amdgcn_mfma_f32_16x16x32_bf16(af[kc], bf, acc[T], 0, 0, 0);
            }
        }

        float bb[16];
        #pragma unroll
        for (int t4 = 0; t4 < 4; ++t4) {
            float4 v = *(const float4*)(b + l15 * 16 + t4 * 4);
            bb[t4*4+0]=v.x; bb[t4*4+1]=v.y; bb[t4*4+2]=v.z; bb[t4*4+3]=v.w;
        }

        #pragma unroll
        for (int r = 0; r < 4; ++r) {
            int orow = r0 + l4 * 4 + r;
            if (orow < Nn) {
                unsigned short o[16];
                #pragma unroll
                for (int T = 0; T < 16; ++T) o[T] = f2bf(acc[T][r] + bb[T]);
                *(uint4*)(Yb + (size_t)orow * HC + l15 * 16)     = *(uint4*)(o);
                *(uint4*)(Yb + (size_t)orow * HC + l15 * 16 + 8) = *(uint4*)(o + 8);
            }
        }
    }
}

// ---- CSR build ----
__global__ __launch_bounds__(256) void scan1_kernel(
    const int* __restrict__ deg, int* __restrict__ off, int* __restrict__ bsum) {
    __shared__ int s[256];
    int i = blockIdx.x * 256 + threadIdx.x;
    int v = (i < Nn) ? deg[i] : 0;
    s[threadIdx.x] = v;
    __syncthreads();
    #pragma unroll
    for (int d = 1; d < 256; d <<= 1) {
        int t = (threadIdx.x >= d) ? s[threadIdx.x - d] : 0;
        __syncthreads();
        s[threadIdx.x] += t;
        __syncthreads();
    }
    if (i < Nn) off[i] = s[threadIdx.x] - v;
    if (threadIdx.x == 255) bsum[blockIdx.x] = s[255];
}
__global__ __launch_bounds__(256) void scan3_kernel(
    int* __restrict__ off, const int* __restrict__ bsum, int* __restrict__ cur) {
    __shared__ int s[256];
    int t = threadIdx.x;
    int v = (t < NB) ? bsum[t] : 0;
    s[t] = v;
    __syncthreads();
    #pragma unroll
    for (int d = 1; d < 256; d <<= 1) {
        int tv = (t >= d) ? s[t - d] : 0;
        __syncthreads();
        s[t] += tv;
        __syncthreads();
    }
    int base = (blockIdx.x == 0) ? 0 : s[blockIdx.x - 1];
    int i = blockIdx.x * 256 + t;
    if (i < Nn) {
        int o = off[i] + base;
        off[i] = o;
        cur[i] = o;
    }
}
__global__ __launch_bounds__(256) void scatter_kernel(
    const int* __restrict__ ei, int* __restrict__ cur,
    int* __restrict__ csr_e, int* __restrict__ csr_s) {
    int e = blockIdx.x * 256 + threadIdx.x;
    if (e >= Ee) return;
    int d = ei[Ee + e];
    int pos = atomicAdd(cur + d, 1);
    csr_e[pos] = e;
    csr_s[pos] = ei[e];
}

// ---- K2: FUSED per-node logits (MFMA) + online softmax + aggregation ----
// v2: 8-edge chunks -> LDS 17.4 KB/block -> 8 blocks/CU = FULL 32 wave slots
// (R18's failure was 34 KB -> 4 blocks -> occ 35%). One wave per node.
//  phase A: e-term via MFMA (M half-padded, MfmaUtil irrelevant); xl rows
//    gathered once, cached to LDS; xr row chunk-uniform (dst=n); logits->LDS.
//    sigma(a)=(a&3)*4+(a>>2) slot perm keeps the C-row loop wave-uniform.
//  phase B: online softmax over 8 slots (xor 4/8/16 class reduce, lanes<32)
//    + aggregation reading rows from LDS. Same-wave LDS -> no barriers.
__global__ __launch_bounds__(256) void fused_node_kernel(
    const unsigned short* __restrict__ xlb, const unsigned short* __restrict__ xrb,
    const int* __restrict__ csr_e, const int* __restrict__ csr_s,
    const float* __restrict__ ea, const unsigned short* __restrict__ wef,
    const float* __restrict__ att, const int* __restrict__ off,
    const int* __restrict__ deg, const float* __restrict__ bias,
    float* __restrict__ out)
{
    __shared__ unsigned short cache[4][8][256];   // 16 KB: xl rows, bf16
    __shared__ float sAl[4][32];                  // logits: slot*4 + head
    __shared__ float shw[4][32];                  // weights: slot*4 + head
    const int lane = threadIdx.x & 63;
    const int wv   = threadIdx.x >> 6;
    const int l15  = lane & 15, l4 = lane >> 4;
    const int n    = blockIdx.x * 4 + wv;
    if (n >= Nn) return;

    const int start = off[n];
    const int len   = deg[n];

    if (len == 0) {
        if (lane < 16) {
            float4 b4 = *(const float4*)(bias + lane * 4);
            *(float4*)(out + (size_t)n * OUTC + lane * 4) = b4;
        }
        return;
    }

    const int sA   = (l15 & 3) * 4 + (l15 >> 2);  // A-row -> edge slot perm
    const int eidx = lane >> 2;                   // staging: edge slot
    const int hagg = lane >> 4;                   // aggregation head

    float m = -3.4e38f, d = 0.f;
    float4 acc = make_float4(0.f, 0.f, 0.f, 0.f);

    for (int c0 = 0; c0 < len; c0 += 8) {
        const int cl   = (len - c0 < 8) ? (len - c0) : 8;
        const int rmax = (cl + 3) >> 2;           // 1 or 2, wave-uniform

        // ---- phase A: logits + LDS row caching ----
        short8 afrag;
        {
            int sc_ = (sA < cl) ? sA : (cl - 1);
            int e = csr_e[start + c0 + sc_];
            const f32x4* pp = (const f32x4*)(ea + (size_t)e * EDIM + l4 * 8);
            f32x4 v0 = __builtin_nontemporal_load(pp);
            f32x4 v1 = __builtin_nontemporal_load(pp + 1);
            afrag[0]=(short)f2bf(v0.x); afrag[1]=(short)f2bf(v0.y);
            afrag[2]=(short)f2bf(v0.z); afrag[3]=(short)f2bf(v0.w);
            afrag[4]=(short)f2bf(v1.x); afrag[5]=(short)f2bf(v1.y);
            afrag[6]=(short)f2bf(v1.z); afrag[7]=(short)f2bf(v1.w);
        }

        unsigned soff[2];
        #pragma unroll
        for (int r = 0; r < 2; ++r) {
            int slot = r * 4 + l4;
            int sc_ = (slot < cl) ? slot : (cl - 1);
            soff[r] = (unsigned)csr_s[start + c0 + sc_] * (unsigned)HC;
        }

        #pragma unroll 1
        for (int cb = 0; cb < 4; ++cb) {
            f32x4 acc4[4];
            const f32x4 z = {0.f, 0.f, 0.f, 0.f};
            #pragma unroll
            for (int nt = 0; nt < 4; ++nt) {
                short8 bfrag = *(const short8*)(wef + ((size_t)(cb * 4 + nt) * 64 + lane) * 8);
                acc4[nt] = __builtin_amdgcn_mfma_f32_16x16x32_bf16(afrag, bfrag, z, 0, 0, 0);
            }

            const unsigned cc = (unsigned)(cb * 64 + l15 * 4);
            ushort4 gr4 = *(const ushort4*)(xrb + (size_t)n * HC + cc);
            f32x2 gr01 = {bf2f(gr4.x), bf2f(gr4.y)};
            f32x2 gr23 = {bf2f(gr4.z), bf2f(gr4.w)};
            float4 atv = *(const float4*)(att + cc);
            f32x2 at01 = {atv.x, atv.y};
            f32x2 at23 = {atv.z, atv.w};

            #pragma unroll
            for (int r = 0; r < 2; ++r) {
                if (r < rmax) {                       // wave-uniform skip
                    int slot = r * 4 + l4;
                    ushort4 gl4 = *(const ushort4*)(xlb + soff[r] + cc);
                    *(ushort4*)(&cache[wv][slot][cc]) = gl4;
                    f32x2 m01 = {acc4[0][r], acc4[1][r]};
                    f32x2 m23 = {acc4[2][r], acc4[3][r]};
                    f32x2 gl01 = {bf2f(gl4.x), bf2f(gl4.y)};
                    f32x2 gl23 = {bf2f(gl4.z), bf2f(gl4.w)};
                    m01 = m01 + gl01 + gr01;
                    m23 = m23 + gl23 + gr23;
                    m01 = __builtin_elementwise_max(m01, m01 * NEG);
                    m23 = __builtin_elementwise_max(m23, m23 * NEG);
                    f32x2 pf = at01 * m01 + at23 * m23;
                    float p = pf.x + pf.y;
                    p = row_sum16(p);
                    if (l15 == 0) sAl[wv][slot * 4 + cb] = p;
                }
            }
        }

        // ---- phase B: online softmax + aggregation from LDS ----
        float a = (eidx < cl) ? sAl[wv][lane & 31] : -3.4e38f;
        float cm = a;
        cm = fmaxf(cm, __shfl_xor(cm, 4, 64));
        cm = fmaxf(cm, __shfl_xor(cm, 8, 64));
        cm = fmaxf(cm, __shfl_xor(cm, 16, 64));
        float mn = fmaxf(m, cm);
        float sc = __expf(m - mn);            // 0 on first chunk
        float w  = (eidx < cl) ? __expf(a - mn) : 0.f;
        float ws = w;
        ws += __shfl_xor(ws, 4, 64);
        ws += __shfl_xor(ws, 8, 64);
        ws += __shfl_xor(ws, 16, 64);
        d = d * sc + ws;
        m = mn;
        if (lane < 32) shw[wv][lane] = w;
        float sca = __shfl(sc, hagg, 64);     // lanes 0-3 hold per-head sc
        acc.x *= sca; acc.y *= sca; acc.z *= sca; acc.w *= sca;
        #pragma unroll 4
        for (int i = 0; i < cl; ++i) {
            float wi = shw[wv][i * 4 + hagg];
            ushort4 g = *(const ushort4*)(&cache[wv][i][lane * 4]);
            acc.x = fmaf(wi, bf2f(g.x), acc.x);
            acc.y = fmaf(wi, bf2f(g.y), acc.y);
            acc.z = fmaf(wi, bf2f(g.z), acc.z);
            acc.w = fmaf(wi, bf2f(g.w), acc.w);
        }
    }

    float dh = __shfl(d, hagg, 64);
    float di = 1.f / dh;
    float4 r;
    r.x = acc.x * di; r.y = acc.y * di; r.z = acc.z * di; r.w = acc.w * di;
    r.x += __shfl_xor(r.x, 16, 64); r.y += __shfl_xor(r.y, 16, 64);
    r.z += __shfl_xor(r.z, 16, 64); r.w += __shfl_xor(r.w, 16, 64);
    r.x += __shfl_xor(r.x, 32, 64); r.y += __shfl_xor(r.y, 32, 64);
    r.z += __shfl_xor(r.z, 32, 64); r.w += __shfl_xor(r.w, 32, 64);
    if (lane < 16) {
        float4 b4 = *(const float4*)(bias + lane * 4);
        float4 o = make_float4(b4.x + 0.25f * r.x, b4.y + 0.25f * r.y,
                               b4.z + 0.25f * r.z, b4.w + 0.25f * r.w);
        *(float4*)(out + (size_t)n * OUTC + lane * 4) = o;
    }
}

extern "C" void kernel_launch(void* const* d_in, const int* in_sizes, int n_in,
                              void* d_out, int out_size, void* d_ws, size_t ws_size,
                              hipStream_t stream)
{
    const float* x    = (const float*)d_in[0];
    const int*   ei   = (const int*)d_in[1];
    const float* ea   = (const float*)d_in[2];
    const float* Wl   = (const float*)d_in[3];
    const float* bl   = (const float*)d_in[4];
    const float* Wr   = (const float*)d_in[5];
    const float* br   = (const float*)d_in[6];
    const float* We   = (const float*)d_in[7];
    const float* att  = (const float*)d_in[8];
    const float* bias = (const float*)d_in[9];
    float* out = (float*)d_out;

    // workspace layout (~56 MB)
    unsigned short* xlb   = (unsigned short*)d_ws;                 // N*256 bf16
    unsigned short* xrb   = xlb + (size_t)Nn * HC;                 // N*256 bf16
    unsigned short* wef   = xrb + (size_t)Nn * HC;                 // 8192 bf16
    unsigned short* wlf   = wef + 8192;                            // 32768 bf16
    unsigned short* wrf   = wlf + 32768;                           // 32768 bf16
    int*            deg   = (int*)(wrf + 32768);                   // N
    int*            off   = deg + Nn;                              // N
    int*            cur   = off + Nn;                              // N
    int*            bsum  = cur + Nn;                              // NB
    int*            csr_e = bsum + 256;                            // E
    int*            csr_s = csr_e + Ee;                            // E

    pack_kernel<<<232, 256, 0, stream>>>(Wl, Wr, We, wlf, wrf, wef, deg);
    gemm_hist_kernel<<<GEMMB + (Ee + 255) / 256, 256, 0, stream>>>(
        x, wlf, bl, wrf, br, xlb, xrb, ei, deg);
    scan1_kernel<<<NB, 256, 0, stream>>>(deg, off, bsum);
    scan3_kernel<<<NB, 256, 0, stream>>>(off, bsum, cur);
    scatter_kernel<<<(Ee + 255) / 256, 256, 0, stream>>>(ei, cur, csr_e, csr_s);
    fused_node_kernel<<<(Nn + 3) / 4, 256, 0, stream>>>(
        xlb, xrb, csr_e, csr_s, ea, wef, att, off, deg, bias, out);
}

// Round 21
// 206.931 us; speedup vs baseline: 1.4221x; 1.4221x over previous
//
#include <hip/hip_runtime.h>
#include <cstddef>

#define Nn 50000
#define Ee 500000
#define INC 128
#define HC 256      // HEADS*OUT_C
#define OUTC 64
#define EDIM 32
#define NEG 0.2f
#define NB 196      // scan blocks = ceil(Nn/256)
#define GEMMB 782   // gemm blocks = ceil(Nn/64)

typedef __attribute__((ext_vector_type(8))) short short8;   // 8 bf16 = 4 VGPR
typedef __attribute__((ext_vector_type(4))) float f32x4;
typedef __attribute__((ext_vector_type(2))) float f32x2;

// ---- bf16 helpers (RNE) ----
__device__ __forceinline__ unsigned short f2bf(float f) {
    unsigned u = __float_as_uint(f);
    return (unsigned short)((u + 0x7FFFu + ((u >> 16) & 1u)) >> 16);
}
__device__ __forceinline__ float bf2f(unsigned short v) {
    return __uint_as_float(((unsigned)v) << 16);
}

// ---- 16-lane row sum via DPP butterfly (pure VALU, no DS pipe) ----
__device__ __forceinline__ float row_sum16(float x) {
    int i;
    i = __builtin_amdgcn_mov_dpp(__float_as_int(x), 0xB1, 0xF, 0xF, true);
    x += __int_as_float(i);
    i = __builtin_amdgcn_mov_dpp(__float_as_int(x), 0x4E, 0xF, 0xF, true);
    x += __int_as_float(i);
    i = __builtin_amdgcn_mov_dpp(__float_as_int(x), 0x141, 0xF, 0xF, true);
    x += __int_as_float(i);
    i = __builtin_amdgcn_mov_dpp(__float_as_int(x), 0x140, 0xF, 0xF, true);
    x += __int_as_float(i);
    return x;
}

// ---- K_pack: Wl/Wr (T-perm) + We (cb-perm) + deg zeroing (fused) ----
__global__ __launch_bounds__(256) void pack_kernel(
    const float* __restrict__ Wl, const float* __restrict__ Wr,
    const float* __restrict__ We,
    unsigned short* __restrict__ wlf, unsigned short* __restrict__ wrf,
    unsigned short* __restrict__ wef, int* __restrict__ deg)
{
    int sid = blockIdx.x * 256 + threadIdx.x;
    if (sid >= 9216) {                 // fused deg zeroing
        int i = sid - 9216;
        if (i < Nn) deg[i] = 0;
        return;
    }
    const float* W; unsigned short* dst; int s; int col; int k0;
    if (sid < 8192) {
        if (sid < 4096) { W = Wl; dst = wlf; s = sid; }
        else            { W = Wr; dst = wrf; s = sid - 4096; }
        int lane = s & 63;
        int T    = (s >> 6) & 15;
        int kc   = s >> 10;
        col = (lane & 15) * 16 + T;
        k0  = kc * 32 + (lane >> 4) * 8;
    } else {
        W = We; dst = wef; s = sid - 8192;
        int lane = s & 63;
        int nt   = (s >> 6) & 3;
        int cb   = s >> 8;
        col = cb * 64 + (lane & 15) * 4 + nt;
        k0  = (lane >> 4) * 8;
    }
    unsigned short tmp[8];
    #pragma unroll
    for (int j = 0; j < 8; ++j) tmp[j] = f2bf(W[(size_t)(k0 + j) * HC + col]);
    *(uint4*)(dst + (size_t)s * 8) = *(uint4*)tmp;
}

// ---- K1: fused gemm (both W, X read once) + hist blocks ----
__global__ __launch_bounds__(256) void gemm_hist_kernel(
    const float* __restrict__ X,
    const unsigned short* __restrict__ wlf, const float* __restrict__ bl,
    const unsigned short* __restrict__ wrf, const float* __restrict__ br,
    unsigned short* __restrict__ Ylb, unsigned short* __restrict__ Yrb,
    const int* __restrict__ ei, int* __restrict__ deg)
{
    if (blockIdx.x >= GEMMB) {
        int e = (blockIdx.x - GEMMB) * 256 + threadIdx.x;
        if (e < Ee) atomicAdd(deg + ei[Ee + e], 1);
        return;
    }

    const int tid = threadIdx.x, lane = tid & 63;
    const int l15 = lane & 15, l4 = lane >> 4;
    const int r0 = blockIdx.x * 64 + (tid >> 6) * 16;

    int arow = r0 + l15; if (arow >= Nn) arow = Nn - 1;
    short8 af[4];
    #pragma unroll
    for (int kc = 0; kc < 4; ++kc) {
        const f32x4* p = (const f32x4*)(X + (size_t)arow * INC + kc * 32 + l4 * 8);
        f32x4 v0 = p[0], v1 = p[1];
        short8 a;
        a[0]=(short)f2bf(v0.x); a[1]=(short)f2bf(v0.y); a[2]=(short)f2bf(v0.z); a[3]=(short)f2bf(v0.w);
        a[4]=(short)f2bf(v1.x); a[5]=(short)f2bf(v1.y); a[6]=(short)f2bf(v1.z); a[7]=(short)f2bf(v1.w);
        af[kc] = a;
    }

    #pragma unroll 1
    for (int w = 0; w < 2; ++w) {
        const unsigned short* wf = w ? wrf : wlf;
        const float* b = w ? br : bl;
        unsigned short* Yb = w ? Yrb : Ylb;

        f32x4 acc[16];
        #pragma unroll
        for (int T = 0; T < 16; ++T) acc[T] = (f32x4){0.f, 0.f, 0.f, 0.f};

        #pragma unroll
        for (int kc = 0; kc < 4; ++kc) {
            #pragma unroll
            for (int T = 0; T < 16; ++T) {
                short8 bf = *(const short8*)(wf + ((size_t)(kc * 16 + T) * 64 + lane) * 8);
                acc[T] = __builtin_amdgcn_mfma_f32_16x16x32_bf16(af[kc], bf, acc[T], 0, 0, 0);
            }
        }

        float bb[16];
        #pragma unroll
        for (int t4 = 0; t4 < 4; ++t4) {
            float4 v = *(const float4*)(b + l15 * 16 + t4 * 4);
            bb[t4*4+0]=v.x; bb[t4*4+1]=v.y; bb[t4*4+2]=v.z; bb[t4*4+3]=v.w;
        }

        #pragma unroll
        for (int r = 0; r < 4; ++r) {
            int orow = r0 + l4 * 4 + r;
            if (orow < Nn) {
                unsigned short o[16];
                #pragma unroll
                for (int T = 0; T < 16; ++T) o[T] = f2bf(acc[T][r] + bb[T]);
                *(uint4*)(Yb + (size_t)orow * HC + l15 * 16)     = *(uint4*)(o);
                *(uint4*)(Yb + (size_t)orow * HC + l15 * 16 + 8) = *(uint4*)(o + 8);
            }
        }
    }
}

// ---- CSR build ----
__global__ __launch_bounds__(256) void scan1_kernel(
    const int* __restrict__ deg, int* __restrict__ off, int* __restrict__ bsum) {
    __shared__ int s[256];
    int i = blockIdx.x * 256 + threadIdx.x;
    int v = (i < Nn) ? deg[i] : 0;
    s[threadIdx.x] = v;
    __syncthreads();
    #pragma unroll
    for (int d = 1; d < 256; d <<= 1) {
        int t = (threadIdx.x >= d) ? s[threadIdx.x - d] : 0;
        __syncthreads();
        s[threadIdx.x] += t;
        __syncthreads();
    }
    if (i < Nn) off[i] = s[threadIdx.x] - v;
    if (threadIdx.x == 255) bsum[blockIdx.x] = s[255];
}
__global__ __launch_bounds__(256) void scan3_kernel(
    int* __restrict__ off, const int* __restrict__ bsum, int* __restrict__ cur) {
    __shared__ int s[256];
    int t = threadIdx.x;
    int v = (t < NB) ? bsum[t] : 0;
    s[t] = v;
    __syncthreads();
    #pragma unroll
    for (int d = 1; d < 256; d <<= 1) {
        int tv = (t >= d) ? s[t - d] : 0;
        __syncthreads();
        s[t] += tv;
        __syncthreads();
    }
    int base = (blockIdx.x == 0) ? 0 : s[blockIdx.x - 1];
    int i = blockIdx.x * 256 + t;
    if (i < Nn) {
        int o = off[i] + base;
        off[i] = o;
        cur[i] = o;
    }
}
__global__ __launch_bounds__(256) void scatter_kernel(
    const int* __restrict__ ei, int* __restrict__ cur,
    int* __restrict__ csr_e, int* __restrict__ csr_s, int* __restrict__ csr_d) {
    int e = blockIdx.x * 256 + threadIdx.x;
    if (e >= Ee) return;
    int d = ei[Ee + e];
    int pos = atomicAdd(cur + d, 1);
    csr_e[pos] = e;
    csr_s[pos] = ei[e];
    csr_d[pos] = d;
}

// ---- K2: per-edge logits via MFMA bf16, CSR-ordered, 16 edges per wave ----
// Epilogue in f32x2 form -> clang SLP-emits v_pk_{add,mul,max,fma}_f32
// (dual-issue packed fp32).
__global__ __launch_bounds__(256) void edge_alpha_kernel(
    const unsigned short* __restrict__ xlb, const unsigned short* __restrict__ xrb,
    const int* __restrict__ csr_e, const int* __restrict__ csr_s,
    const int* __restrict__ csr_d, const float* __restrict__ ea,
    const unsigned short* __restrict__ wef, const float* __restrict__ att,
    float* __restrict__ alpha)
{
    const int tid  = threadIdx.x;
    const int lane = tid & 63;
    const int l15  = lane & 15, l4 = lane >> 4;
    const int p0   = blockIdx.x * 64 + (tid >> 6) * 16;

    // A-frag: row = csr_e[p0 + l15], nontemporal (each ea row read once)
    short8 afrag;
    {
        int p = p0 + l15;
        if (p >= Ee) p = Ee - 1;
        int e = csr_e[p];
        const f32x4* pp = (const f32x4*)(ea + (size_t)e * EDIM + l4 * 8);
        f32x4 v0 = __builtin_nontemporal_load(pp);
        f32x4 v1 = __builtin_nontemporal_load(pp + 1);
        afrag[0]=(short)f2bf(v0.x); afrag[1]=(short)f2bf(v0.y);
        afrag[2]=(short)f2bf(v0.z); afrag[3]=(short)f2bf(v0.w);
        afrag[4]=(short)f2bf(v1.x); afrag[5]=(short)f2bf(v1.y);
        afrag[6]=(short)f2bf(v1.z); afrag[7]=(short)f2bf(v1.w);
    }

    unsigned soff[4], doff[4];
    #pragma unroll
    for (int r = 0; r < 4; ++r) {
        int p = p0 + l4 * 4 + r;
        int pc = (p < Ee) ? p : Ee - 1;
        soff[r] = (unsigned)csr_s[pc] * (unsigned)HC;
        doff[r] = (unsigned)csr_d[pc] * (unsigned)HC;
    }

    #pragma unroll 1
    for (int cb = 0; cb < 4; ++cb) {
        f32x4 acc[4];
        const f32x4 z = {0.f, 0.f, 0.f, 0.f};
        #pragma unroll
        for (int nt = 0; nt < 4; ++nt) {
            short8 bfrag = *(const short8*)(wef + ((size_t)(cb * 4 + nt) * 64 + lane) * 8);
            acc[nt] = __builtin_amdgcn_mfma_f32_16x16x32_bf16(afrag, bfrag, z, 0, 0, 0);
        }

        float4 atv = *(const float4*)(att + cb * 64 + l15 * 4);
        f32x2 at01 = {atv.x, atv.y};
        f32x2 at23 = {atv.z, atv.w};

        #pragma unroll
        for (int r = 0; r < 4; ++r) {
            const unsigned c = (unsigned)(cb * 64 + l15 * 4);
            ushort4 gl4 = *(const ushort4*)(xlb + soff[r] + c);
            ushort4 gr4 = *(const ushort4*)(xrb + doff[r] + c);
            f32x2 m01 = {acc[0][r], acc[1][r]};
            f32x2 m23 = {acc[2][r], acc[3][r]};
            f32x2 gl01 = {bf2f(gl4.x), bf2f(gl4.y)};
            f32x2 gl23 = {bf2f(gl4.z), bf2f(gl4.w)};
            f32x2 gr01 = {bf2f(gr4.x), bf2f(gr4.y)};
            f32x2 gr23 = {bf2f(gr4.z), bf2f(gr4.w)};
            m01 = m01 + gl01 + gr01;
            m23 = m23 + gl23 + gr23;
            m01 = __builtin_elementwise_max(m01, m01 * NEG);   // leaky, packed
            m23 = __builtin_elementwise_max(m23, m23 * NEG);
            f32x2 pf = at01 * m01 + at23 * m23;                // 2x pk_fma
            float p = pf.x + pf.y;
            p = row_sum16(p);
            int pp = p0 + l4 * 4 + r;
            if (l15 == 0 && pp < Ee)
                alpha[(size_t)pp * 4 + cb] = p;
        }
    }
}

// ---- K4: fused per-node softmax + aggregation, ONE WAVE PER NODE ----
__global__ __launch_bounds__(256) void node_aggr_kernel(
    const unsigned short* __restrict__ xlb,
    const int* __restrict__ csr_s,
    const float* __restrict__ alpha, const int* __restrict__ off,
    const int* __restrict__ deg, const float* __restrict__ bias,
    float* __restrict__ out)
{
    __shared__ float shw[4][64];
    __shared__ int   shs[4][16];
    const int lane = threadIdx.x & 63;
    const int wv   = threadIdx.x >> 6;
    const int n    = blockIdx.x * 4 + wv;
    if (n >= Nn) return;

    const int start = off[n];
    const int len   = deg[n];

    if (len == 0) {
        if (lane < 16) {
            float4 b4 = *(const float4*)(bias + lane * 4);
            *(float4*)(out + (size_t)n * OUTC + lane * 4) = b4;
        }
        return;
    }

    const int eidx = lane >> 2;
    const int hagg = lane >> 4;

    float m = -3.4e38f, d = 0.f;
    f32x2 acc01 = {0.f, 0.f}, acc23 = {0.f, 0.f};

    for (int c0 = 0; c0 < len; c0 += 16) {
        int cl = len - c0; if (cl > 16) cl = 16;
        float a = (eidx < cl) ? alpha[(size_t)(start + c0) * 4 + lane] : -3.4e38f;
        if (lane < cl) shs[wv][lane] = csr_s[start + c0 + lane];
        float cm = a;
        cm = fmaxf(cm, __shfl_xor(cm, 4, 64));
        cm = fmaxf(cm, __shfl_xor(cm, 8, 64));
        cm = fmaxf(cm, __shfl_xor(cm, 16, 64));
        cm = fmaxf(cm, __shfl_xor(cm, 32, 64));
        float mn = fmaxf(m, cm);
        float sc = __expf(m - mn);
        float w  = (eidx < cl) ? __expf(a - mn) : 0.f;
        float ws = w;
        ws += __shfl_xor(ws, 4, 64);
        ws += __shfl_xor(ws, 8, 64);
        ws += __shfl_xor(ws, 16, 64);
        ws += __shfl_xor(ws, 32, 64);
        d = d * sc + ws;
        m = mn;
        shw[wv][lane] = w;
        float sca = __shfl(sc, hagg, 64);
        acc01 *= sca; acc23 *= sca;
        #pragma unroll 4
        for (int i = 0; i < cl; ++i) {
            int   si = shs[wv][i];
            float wi = shw[wv][i * 4 + hagg];
            ushort4 g = *(const ushort4*)(xlb + (size_t)si * HC + lane * 4);
            f32x2 g01 = {bf2f(g.x), bf2f(g.y)};
            f32x2 g23 = {bf2f(g.z), bf2f(g.w)};
            f32x2 wv2 = {wi, wi};
            acc01 = acc01 + wv2 * g01;   // pk_fma
            acc23 = acc23 + wv2 * g23;
        }
    }

    float dh = __shfl(d, hagg, 64);
    float di = 1.f / dh;
    float4 r;
    r.x = acc01.x * di; r.y = acc01.y * di; r.z = acc23.x * di; r.w = acc23.y * di;
    r.x += __shfl_xor(r.x, 16, 64); r.y += __shfl_xor(r.y, 16, 64);
    r.z += __shfl_xor(r.z, 16, 64); r.w += __shfl_xor(r.w, 16, 64);
    r.x += __shfl_xor(r.x, 32, 64); r.y += __shfl_xor(r.y, 32, 64);
    r.z += __shfl_xor(r.z, 32, 64); r.w += __shfl_xor(r.w, 32, 64);
    if (lane < 16) {
        float4 b4 = *(const float4*)(bias + lane * 4);
        float4 o = make_float4(b4.x + 0.25f * r.x, b4.y + 0.25f * r.y,
                               b4.z + 0.25f * r.z, b4.w + 0.25f * r.w);
        *(float4*)(out + (size_t)n * OUTC + lane * 4) = o;
    }
}

extern "C" void kernel_launch(void* const* d_in, const int* in_sizes, int n_in,
                              void* d_out, int out_size, void* d_ws, size_t ws_size,
                              hipStream_t stream)
{
    const float* x    = (const float*)d_in[0];
    const int*   ei   = (const int*)d_in[1];
    const float* ea   = (const float*)d_in[2];
    const float* Wl   = (const float*)d_in[3];
    const float* bl   = (const float*)d_in[4];
    const float* Wr   = (const float*)d_in[5];
    const float* br   = (const float*)d_in[6];
    const float* We   = (const float*)d_in[7];
    const float* att  = (const float*)d_in[8];
    const float* bias = (const float*)d_in[9];
    float* out = (float*)d_out;

    // workspace layout (~66 MB)
    unsigned short* xlb   = (unsigned short*)d_ws;                 // N*256 bf16
    unsigned short* xrb   = xlb + (size_t)Nn * HC;                 // N*256 bf16
    float*          alpha = (float*)(xrb + (size_t)Nn * HC);       // E*4 f32 (CSR order)
    unsigned short* wef   = (unsigned short*)(alpha + (size_t)Ee * 4); // 8192 bf16
    unsigned short* wlf   = wef + 8192;                            // 32768 bf16
    unsigned short* wrf   = wlf + 32768;                           // 32768 bf16
    int*            deg   = (int*)(wrf + 32768);                   // N
    int*            off   = deg + Nn;                              // N
    int*            cur   = off + Nn;                              // N
    int*            bsum  = cur + Nn;                              // NB
    int*            csr_e = bsum + 256;                            // E
    int*            csr_s = csr_e + Ee;                            // E
    int*            csr_d = csr_s + Ee;                            // E

    pack_kernel<<<232, 256, 0, stream>>>(Wl, Wr, We, wlf, wrf, wef, deg);
    gemm_hist_kernel<<<GEMMB + (Ee + 255) / 256, 256, 0, stream>>>(
        x, wlf, bl, wrf, br, xlb, xrb, ei, deg);
    scan1_kernel<<<NB, 256, 0, stream>>>(deg, off, bsum);
    scan3_kernel<<<NB, 256, 0, stream>>>(off, bsum, cur);
    scatter_kernel<<<(Ee + 255) / 256, 256, 0, stream>>>(ei, cur, csr_e, csr_s, csr_d);
    edge_alpha_kernel<<<(Ee + 63) / 64, 256, 0, stream>>>(xlb, xrb, csr_e, csr_s, csr_d, ea, wef, att, alpha);
    node_aggr_kernel<<<(Nn + 3) / 4, 256, 0, stream>>>(xlb, csr_s, alpha, off, deg, bias, out);
}